// Round 12
// baseline (450.370 us; speedup 1.0000x reference)
//
#include <hip/hip_runtime.h>

#define BATCH 8192
#define V 512
#define N1 513
#define KCH 8
#define NCH 64           // chunks of 8 variables
#define RB 32            // rows per block -> grid 256
#define NT 1024          // 16 waves in ONE block -> 4 waves/SIMD guaranteed
#define PKS 520          // Phi row stride (bf16 elems), 1040B rows (16B aligned)
#define SJ 260           // S row stride (floats), 256 + 4 pad

typedef __bf16 bf16_t;
typedef bf16_t bf16x8 __attribute__((ext_vector_type(8)));
typedef float f32x4 __attribute__((ext_vector_type(4)));
typedef float f32x2 __attribute__((ext_vector_type(2)));

// workspace: Mhi (fragment-linear triangular pack, mat=1 tiles PRE-NEGATED),
// Dv (fp32, pre-scaled by mat sign), Bv (fp32, pre-negated mat=1).
// Chunk cc in 1..63: klen = 8*cc, nkb = ceil(cc/4) k-blocks of 32 (zero-padded).
// kb-blocks before cc: S(cc-1), S(n) = 2q(q+1)+s(q+1), q=n>>2, s=n&3 (total 528).
// elem = base + kb*8192 + t*512 + lane*8 + jj ; t = 2*vlo + mat (tile of 16 j),
// lane = c + 16*q, k = kb*32 + 8*q + jj ; j = c + 16*mat + 32*vlo in [0,256).
// Dv: [cc][vl][256 j] ; Bv: [cc][256 j].
#define MHI_ELEMS 4325376ull     // 528 * 8192
#define DV_OFF (MHI_ELEMS * 2ull)
#define BV_OFF (DV_OFF + 524288ull)

__device__ __forceinline__ f32x4 mfma16(bf16x8 a, bf16x8 b, f32x4 c) {
    return __builtin_amdgcn_mfma_f32_16x16x32_bf16(a, b, c, 0, 0, 0);
}

// ---- unified repack: blocks 0..1007 pack Mhi; 1008..1583 pack Dv/Bv -----------
__global__ __launch_bounds__(256)
void repack_all(const float* __restrict__ pos, const float* __restrict__ neg,
                bf16_t* __restrict__ Mhi, float* __restrict__ Dv,
                float* __restrict__ Bv)
{
    const int bx = blockIdx.x;
    if (bx < 1008) {
        const int cc  = (bx >> 4) + 1;       // 1..63
        const int kb  = bx & 15;
        const int nkb = (cc + 3) >> 2;
        if (kb >= nkb) return;
        const int klen = 8 * cc;
        const int qq = (cc - 1) >> 2, ss = (cc - 1) & 3;
        const size_t base = ((size_t)(2 * qq * (qq + 1) + ss * (qq + 1)) + kb) * 8192ull;
        for (int e = threadIdx.x; e < 8192; e += 256) {
            const int t = e >> 9, s5 = (e >> 3) & 63, jj = e & 7;
            const int c = s5 & 15, q = s5 >> 4;
            const int v = cc * 8 + (t >> 1);
            const int k = kb * 32 + 8 * q + jj;
            const float* src = (t & 1) ? neg : pos;
            float x = (k < klen) ? src[(size_t)(v * 16 + c) * N1 + k] : 0.0f;
            if (t & 1) x = -x;               // pre-negate mat=1
            Mhi[base + e] = (bf16_t)x;
        }
    } else {
        const int e = (bx - 1008) * 256 + threadIdx.x;
        if (e < 131072) {                    // Dv: 64 cc x 8 vl x 256 j
            const int cc = e >> 11, vl = (e >> 8) & 7, j = e & 255;
            const int v = cc * 8 + (j >> 5), c = j & 15;
            const float* src = (j & 16) ? neg : pos;
            const float x = src[(size_t)(v * 16 + c) * N1 + cc * 8 + vl];
            Dv[e] = (j & 16) ? -x : x;
        } else {                             // Bv: 64 cc x 256 j
            const int e2 = e - 131072;
            const int cc = e2 >> 8, j = e2 & 255;
            const int v = cc * 8 + (j >> 5), c = j & 15;
            const float* src = (j & 16) ? neg : pos;
            const float x = src[(size_t)(v * 16 + c) * N1 + V];
            Bv[e2] = (j & 16) ? -x : x;
        }
    }
}

// ---- fused main kernel: 32 rows, 16 waves, grid 256, 8-var chunks --------------
// Wave w: GEMM j-tile t = w (16 j), both row halves (acc[2]); chain rows 2w,2w+1.
// Per chunk: dump acc -> S, barrier, 8-step in-wave chain (lane owns j=4l..4l+3;
// lane = cquad + 4*mat + 8*vlo) interleaving up to 2 bulk k-blocks of chunk cc+1
// per step, barrier, final zero-padded k-block. mat=1 negated end-to-end.
__global__ __launch_bounds__(NT)
void shield_fused(const float* __restrict__ preds,
                  const bf16_t* __restrict__ Mhi,
                  const float* __restrict__ Dv, const float* __restrict__ Bv,
                  float* __restrict__ out)
{
    __shared__ bf16_t Phi[RB * PKS];   // 33,280 B
    __shared__ float  S[RB * SJ];      // 33,280 B  (total 66,560)

    const int tid  = threadIdx.x;
    const int b0   = blockIdx.x * RB;
    const int lane = tid & 63;
    const int w    = tid >> 6;          // 0..15
    const int cq   = lane & 15;
    const int q    = lane >> 4;
    const int rp0  = w * 2;             // chain rows 2w, 2w+1

    // ---- load preds -> Phi ----
    {
        const int r = tid >> 5, seg = tid & 31;
        const float* prow = preds + (size_t)(b0 + r) * V + seg * 16;
        #pragma unroll
        for (int k = 0; k < 16; k += 4) {
            const float4 p4 = *(const float4*)(prow + k);
            const int n = seg * 16 + k;
            Phi[r * PKS + n + 0] = (bf16_t)p4.x;
            Phi[r * PKS + n + 1] = (bf16_t)p4.y;
            Phi[r * PKS + n + 2] = (bf16_t)p4.z;
            Phi[r * PKS + n + 3] = (bf16_t)p4.w;
        }
    }

    const int j0    = 16 * w + cq;       // wave's tile column
    const int aoff0 = cq * PKS + 8 * q;
    const int aoff1 = (16 + cq) * PKS + 8 * q;

    // acc(0) = bias(0) (chunk 0 references only the bias column)
    f32x4 acc[2];
    {
        const float b = Bv[j0];
        acc[0] = f32x4{b, b, b, b};
        acc[1] = f32x4{b, b, b, b};
    }

    #pragma unroll 1
    for (int cc = 0; cc < NCH; ++cc) {
        const int v0 = cc * 8;
        const int  ccn  = cc + 1;
        const bool hasN = ccn < NCH;
        const int  nkbN = hasN ? ((ccn + 3) >> 2) : 0;
        const int  qq = (ccn - 1) >> 2, ss = (ccn - 1) & 3;
        const bf16_t* phN = Mhi + 8192ull * (size_t)(2 * qq * (qq + 1) + ss * (qq + 1))
                          + (size_t)w * 512 + (size_t)lane * 8;

        // ---- dump acc(cc) -> S ----
        #pragma unroll
        for (int reg = 0; reg < 4; ++reg) {
            S[(4 * q + reg) * SJ + j0]      = acc[0][reg];
            S[(16 + 4 * q + reg) * SJ + j0] = acc[1][reg];
        }
        __syncthreads();   // (A) S ready; prior Phi writes visible

        // ---- load s2: lane owns j = 4*lane..4*lane+3, rows 2w / 2w+1 ----
        f32x2 s2[4];
        {
            const float4 a0 = *(const float4*)(&S[rp0 * SJ + 4 * lane]);
            const float4 c0 = *(const float4*)(&S[(rp0 + 1) * SJ + 4 * lane]);
            s2[0] = f32x2{a0.x, c0.x}; s2[1] = f32x2{a0.y, c0.y};
            s2[2] = f32x2{a0.z, c0.z}; s2[3] = f32x2{a0.w, c0.w};
        }

        // ---- init acc(ccn) with bias ----
        if (hasN) {
            const float b = Bv[(ccn << 8) + j0];
            acc[0] = f32x4{b, b, b, b};
            acc[1] = f32x4{b, b, b, b};
        }

        // ---- 8-step serial chain + up to 2 interleaved bulk k-blocks/step ----
        #pragma unroll
        for (int vl = 0; vl < KCH; ++vl) {
            const int vcur = v0 + vl;
            const bool doA = hasN && (vl < nkbN - 1);
            const bool doB = hasN && (vl + 8 < nkbN - 1);

            bf16x8 faA0, faA1, fbA, faB0, faB1, fbB;
            if (doA) {
                const int k0 = vl * 32;
                faA0 = *(const bf16x8*)(Phi + aoff0 + k0);
                faA1 = *(const bf16x8*)(Phi + aoff1 + k0);
                fbA  = *(const bf16x8*)(phN + (size_t)vl * 8192);
            }
            if (doB) {
                const int k0 = (vl + 8) * 32;
                faB0 = *(const bf16x8*)(Phi + aoff0 + k0);
                faB1 = *(const bf16x8*)(Phi + aoff1 + k0);
                fbB  = *(const bf16x8*)(phN + (size_t)(vl + 8) * 8192);
            }

            // this step's dv (1 coalesced dwordx4) and po (LDS); used post-reduce
            float dv[4], po[2];
            {
                const float4 d0 = *(const float4*)(Dv + ((size_t)vcur << 8) + 4 * lane);
                dv[0] = d0.x; dv[1] = d0.y; dv[2] = d0.z; dv[3] = d0.w;
                po[0] = (float)Phi[rp0 * PKS + vcur];
                po[1] = (float)Phi[(rp0 + 1) * PKS + vcur];
            }

            // packed in-lane reduce 4 -> 1 (both rows), then c-quad merge (xor1,2)
            const f32x2 mx = __builtin_elementwise_max(
                                 __builtin_elementwise_max(s2[0], s2[1]),
                                 __builtin_elementwise_max(s2[2], s2[3]));
            float red[2];
            #pragma unroll
            for (int r = 0; r < 2; ++r) {
                float m = mx[r];
                m = fmaxf(m, __shfl_xor(m, 1, 64));
                m = fmaxf(m, __shfl_xor(m, 2, 64));
                red[r] = m;
            }
            float pc[2];
            #pragma unroll
            for (int r = 0; r < 2; ++r) {
                const float lw  = __shfl(red[r], 8 * vl, 64);       // lower
                const float nup = __shfl(red[r], 8 * vl + 4, 64);   // -upper
                pc[r] = fminf(fmaxf(po[r], lw), -nup);
            }
            if (lane == 8 * vl) {
                Phi[rp0 * PKS + vcur]       = (bf16_t)pc[0];
                Phi[(rp0 + 1) * PKS + vcur] = (bf16_t)pc[1];
            }
            // rank-1 update (packed fp32 fma; Dv pre-scaled so no sign mul)
            const f32x2 pcv = {pc[0], pc[1]};
            #pragma unroll
            for (int jj = 0; jj < 4; ++jj) {
                const f32x2 dsp = {dv[jj], dv[jj]};
                s2[jj] = __builtin_elementwise_fma(dsp, pcv, s2[jj]);
            }

            if (doA) {
                acc[0] = mfma16(faA0, fbA, acc[0]);
                acc[1] = mfma16(faA1, fbA, acc[1]);
            }
            if (doB) {
                acc[0] = mfma16(faB0, fbB, acc[0]);
                acc[1] = mfma16(faB1, fbB, acc[1]);
            }
        }

        __syncthreads();   // (D) fresh Phi columns visible; S safe to reuse

        // ---- final k-block of chunk ccn (zero-padded B -> exact no-ops) ----
        if (hasN) {
            const int k0 = (nkbN - 1) * 32;
            const bf16x8 fa0 = *(const bf16x8*)(Phi + aoff0 + k0);
            const bf16x8 fa1 = *(const bf16x8*)(Phi + aoff1 + k0);
            const bf16x8 fb  = *(const bf16x8*)(phN + (size_t)(nkbN - 1) * 8192);
            acc[0] = mfma16(fa0, fb, acc[0]);
            acc[1] = mfma16(fa1, fb, acc[1]);
        }
    }

    // ---- epilogue ----
    {
        const int r = tid >> 5, seg = tid & 31;
        float* orow = out + (size_t)(b0 + r) * V + seg * 16;
        #pragma unroll
        for (int k = 0; k < 16; k += 4) {
            const int n = seg * 16 + k;
            float4 o;
            o.x = (float)Phi[r * PKS + n + 0];
            o.y = (float)Phi[r * PKS + n + 1];
            o.z = (float)Phi[r * PKS + n + 2];
            o.w = (float)Phi[r * PKS + n + 3];
            *(float4*)(orow + k) = o;
        }
    }
}

extern "C" void kernel_launch(void* const* d_in, const int* in_sizes, int n_in,
                              void* d_out, int out_size, void* d_ws, size_t ws_size,
                              hipStream_t stream) {
    const float* preds = (const float*)d_in[0];
    const float* pos   = (const float*)d_in[1];
    const float* neg   = (const float*)d_in[2];
    float* o = (float*)d_out;
    char* base = (char*)d_ws;
    bf16_t* Mhi = (bf16_t*)base;
    float*  Dv  = (float*)(base + DV_OFF);
    float*  Bv  = (float*)(base + BV_OFF);
    repack_all<<<dim3(1584), 256, 0, stream>>>(pos, neg, Mhi, Dv, Bv);
    shield_fused<<<dim3(BATCH / RB), NT, 0, stream>>>(preds, Mhi, Dv, Bv, o);
}